// Round 2
// baseline (195.451 us; speedup 1.0000x reference)
//
#include <hip/hip_runtime.h>

// PureQNet: pool(64x64 -> 4x4) -> normalize -> 4-qubit RX+CNOT-ring circuit
// (depth 6) -> |psi|^2 -> Z/ZZ expectations -> 10x10 head -> *scale.
// Memory-bound: 134 MB input read dominates. One block per image.

#define QNET_NQ 4
#define QNET_DEPTH 6

__global__ __launch_bounds__(256) void qnet_kernel(
    const float* __restrict__ x,        // (B, 1, 64, 64)
    const float* __restrict__ qw,       // (6, 4)
    const float* __restrict__ head_w,   // (10, 10)
    const float* __restrict__ head_b,   // (10,)
    const float* __restrict__ scale,    // (1,)
    float* __restrict__ out)            // (B, 10)
{
    const int b    = blockIdx.x;
    const int t    = threadIdx.x;
    const int wave = t >> 6;
    const int lane = t & 63;

    __shared__ float pooled[16];

    // ---- adaptive avg pool to 4x4: wave w owns image rows [16w, 16w+16) ----
    // element offset = 1024*w + 4*(lane + 64*i): per-load, consecutive lanes
    // touch consecutive 16B (perfect coalescing). All 16 floats of a thread
    // land in pooled bin (w, (lane%16)/4).
    const float* img = x + (size_t)b * 4096 + (size_t)wave * 1024;
    float s = 0.f;
#pragma unroll
    for (int i = 0; i < 4; ++i) {
        float4 v = *reinterpret_cast<const float4*>(img + 4 * (lane + 64 * i));
        s += v.x + v.y + v.z + v.w;
    }
    // reduce the 16-lane class {lanes with same (lane%16)>>2}: bits {0,1,4,5}
    s += __shfl_xor(s, 32);
    s += __shfl_xor(s, 16);
    s += __shfl_xor(s, 2);
    s += __shfl_xor(s, 1);
    if (lane < 16 && (lane & 3) == 0)
        pooled[wave * 4 + (lane >> 2)] = s * (1.0f / 256.0f);
    __syncthreads();

    if (wave != 0) return;  // wave 0 finishes the image

    // ---- amplitude embedding (normalize) ----
    const int idx = lane & 15;          // lane -> amplitude index (wire0 = MSB)
    float v  = pooled[idx];
    float n2 = v * v;
    n2 += __shfl_xor(n2, 1);
    n2 += __shfl_xor(n2, 2);
    n2 += __shfl_xor(n2, 4);
    n2 += __shfl_xor(n2, 8);
    const float inv = rsqrtf(n2);
    float re = v * inv;
    float im = 0.f;

    // ---- circuit: DEPTH x { RX(w[l,q]) on each qubit; CNOT ring } ----
#pragma unroll
    for (int l = 0; l < QNET_DEPTH; ++l) {
#pragma unroll
        for (int q = 0; q < QNET_NQ; ++q) {
            const float half = 0.5f * qw[l * QNET_NQ + q];
            float sn, cs;
            sincosf(half, &sn, &cs);
            const int bit = 1 << (3 - q);           // wire q = bit (3-q)
            const float re_p = __shfl_xor(re, bit);
            const float im_p = __shfl_xor(im, bit);
            // new = c*self - i*s*partner  (symmetric for both halves)
            re = cs * re + sn * im_p;
            im = cs * im - sn * re_p;
        }
#pragma unroll
        for (int q = 0; q < QNET_NQ; ++q) {         // CNOT(q -> (q+1)%4)
            const int cb = 1 << (3 - q);
            const int tb = 1 << (3 - ((q + 1) & 3));
            const float re_s = __shfl_xor(re, tb);
            const float im_s = __shfl_xor(im, tb);
            const bool ctrl = (idx & cb) != 0;
            re = ctrl ? re_s : re;
            im = ctrl ? im_s : im;
        }
    }

    const float prob = re * re + im * im;

    // ---- out[r] = (sum_idx prob[idx] * M[r][idx] + b[r]) * scale,
    //      M[r][idx] = sum_k head_w[r][k] * Zsign_k(idx)  (signs compile-time)
    const int r = (lane < 10) ? lane : 0;
    float hw[10];
#pragma unroll
    for (int k = 0; k < 10; ++k) hw[k] = head_w[r * 10 + k];

    float acc = head_b[r];
#pragma unroll
    for (int i2 = 0; i2 < 16; ++i2) {
        const float p  = __shfl(prob, i2);
        const float z0 = (i2 & 8) ? -1.f : 1.f;
        const float z1 = (i2 & 4) ? -1.f : 1.f;
        const float z2 = (i2 & 2) ? -1.f : 1.f;
        const float z3 = (i2 & 1) ? -1.f : 1.f;
        const float m = z0 * hw[0] + z1 * hw[1] + z2 * hw[2] + z3 * hw[3]
                      + (z0 * z1) * hw[4] + (z0 * z2) * hw[5] + (z0 * z3) * hw[6]
                      + (z1 * z2) * hw[7] + (z1 * z3) * hw[8] + (z2 * z3) * hw[9];
        acc += p * m;
    }
    if (lane < 10)
        out[(size_t)b * 10 + lane] = acc * scale[0];
}

extern "C" void kernel_launch(void* const* d_in, const int* in_sizes, int n_in,
                              void* d_out, int out_size, void* d_ws, size_t ws_size,
                              hipStream_t stream) {
    const float* x      = (const float*)d_in[0];
    const float* qw     = (const float*)d_in[1];
    const float* head_w = (const float*)d_in[2];
    const float* head_b = (const float*)d_in[3];
    const float* scale  = (const float*)d_in[4];
    float* out = (float*)d_out;

    const int B = in_sizes[0] / 4096;   // 8192
    qnet_kernel<<<B, 256, 0, stream>>>(x, qw, head_w, head_b, scale, out);
}